// Round 3
// baseline (431.648 us; speedup 1.0000x reference)
//
#include <hip/hip_runtime.h>

typedef __bf16 bf16_t;
typedef __bf16 bf16x8 __attribute__((ext_vector_type(8)));
typedef __bf16 bf16x4 __attribute__((ext_vector_type(4)));
typedef float  f32x4  __attribute__((ext_vector_type(4)));

#define LOG2E 1.44269504088896340736f

// ---------------- RoPE table: cos/sin [S][32] ----------------
__global__ __launch_bounds__(256) void rope_table_k(float* __restrict__ cs,
                                                    float* __restrict__ sn, int S) {
  int i = blockIdx.x * 256 + threadIdx.x;
  if (i >= S * 32) return;
  int s = i >> 5, j = i & 31;
  float theta = powf(10000.0f, -(float)j * (1.0f / 32.0f));
  float a = (float)s * theta;
  cs[i] = cosf(a);
  sn[i] = sinf(a);
}

// ---------------- f32 -> bf16 cast (x4 vectorized) ----------------
__global__ __launch_bounds__(256) void cast_bf16_k(const float* __restrict__ in,
                                                   bf16_t* __restrict__ out, int n4) {
  int i = blockIdx.x * 256 + threadIdx.x;
  if (i >= n4) return;
  const float4 v = ((const float4*)in)[i];
  bf16x4 o;
  o[0] = (bf16_t)v.x; o[1] = (bf16_t)v.y; o[2] = (bf16_t)v.z; o[3] = (bf16_t)v.w;
  ((bf16x4*)out)[i] = o;
}

// ---------------- f32 (R x C) -> bf16 transpose (C x R) ----------------
__global__ void transpose_cast_k(const float* __restrict__ in, bf16_t* __restrict__ out,
                                 int R, int C) {
  __shared__ float tile[32][33];
  int c0 = blockIdx.x * 32, r0 = blockIdx.y * 32;
  int tx = threadIdx.x, ty = threadIdx.y;  // (32,8)
  #pragma unroll
  for (int k = 0; k < 32; k += 8)
    tile[ty + k][tx] = in[(size_t)(r0 + ty + k) * C + c0 + tx];
  __syncthreads();
  #pragma unroll
  for (int k = 0; k < 32; k += 8)
    out[(size_t)(c0 + ty + k) * R + r0 + tx] = (bf16_t)tile[tx][ty + k];
}

// ---------------- bf16 GEMM: C = A(MxK) * BT(NxK)^T, fused epilogues ----------------
// mode 0: RoPE + 0.125 scale, store bf16 q[h][s][64]   (h = col/64)
// mode 1: RoPE,               store bf16 k[g][s][64]
// mode 2: plain,              store bf16 vT[g][64][s]  (transposed)
// mode 3: + bias,             store f32  out[s][col]
__global__ __launch_bounds__(256) void gemm_bf16_k(
    const bf16_t* __restrict__ A, const bf16_t* __restrict__ BT,
    const int M, const int N, const int K, const int mode,
    const float* __restrict__ cs, const float* __restrict__ sn,
    bf16_t* __restrict__ obf, float* __restrict__ ofp,
    const float* __restrict__ bias, const int S) {
  __shared__ bf16_t a_lds[128][40];
  __shared__ bf16_t b_lds[128][40];
  const int tid = threadIdx.x;
  const int wid = tid >> 6, lane = tid & 63;
  const int fr = lane & 15, kg = lane >> 4;
  const int row0 = blockIdx.y * 128, col0 = blockIdx.x * 128;
  const int wr = (wid >> 1) * 64, wc = (wid & 1) * 64;

  f32x4 acc[4][4];
  #pragma unroll
  for (int i = 0; i < 4; ++i)
    #pragma unroll
    for (int j = 0; j < 4; ++j)
      acc[i][j] = (f32x4){0.f, 0.f, 0.f, 0.f};

  const int r0 = tid >> 2, sg0 = tid & 3;  // chunk 0 (rows 0..63)
  const int r1 = 64 + r0;                  // chunk 1 (rows 64..127)

  for (int kt = 0; kt < K; kt += 32) {
    bf16x8 av0 = *(const bf16x8*)&A [(size_t)(row0 + r0) * K + kt + sg0 * 8];
    bf16x8 av1 = *(const bf16x8*)&A [(size_t)(row0 + r1) * K + kt + sg0 * 8];
    bf16x8 bv0 = *(const bf16x8*)&BT[(size_t)(col0 + r0) * K + kt + sg0 * 8];
    bf16x8 bv1 = *(const bf16x8*)&BT[(size_t)(col0 + r1) * K + kt + sg0 * 8];
    __syncthreads();
    *(bf16x8*)&a_lds[r0][sg0 * 8] = av0;
    *(bf16x8*)&a_lds[r1][sg0 * 8] = av1;
    *(bf16x8*)&b_lds[r0][sg0 * 8] = bv0;
    *(bf16x8*)&b_lds[r1][sg0 * 8] = bv1;
    __syncthreads();
    bf16x8 af[4], bfr[4];
    #pragma unroll
    for (int mi = 0; mi < 4; ++mi) af[mi]  = *(const bf16x8*)&a_lds[wr + mi * 16 + fr][kg * 8];
    #pragma unroll
    for (int ni = 0; ni < 4; ++ni) bfr[ni] = *(const bf16x8*)&b_lds[wc + ni * 16 + fr][kg * 8];
    #pragma unroll
    for (int mi = 0; mi < 4; ++mi)
      #pragma unroll
      for (int ni = 0; ni < 4; ++ni)
        acc[mi][ni] = __builtin_amdgcn_mfma_f32_16x16x32_bf16(af[mi], bfr[ni], acc[mi][ni], 0, 0, 0);
  }

  #pragma unroll
  for (int mi = 0; mi < 4; ++mi) {
    #pragma unroll
    for (int ni = 0; ni < 4; ++ni) {
      #pragma unroll
      for (int r = 0; r < 4; ++r) {
        const int grow = row0 + wr + mi * 16 + kg * 4 + r;  // C row = 4*(lane>>4)+reg
        const int gcol = col0 + wc + ni * 16 + fr;          // C col = lane&15
        float v = acc[mi][ni][r];
        if (mode == 3) {
          ofp[(size_t)grow * N + gcol] = v + bias[gcol];
        } else if (mode == 2) {
          const int gi = gcol >> 6, d = gcol & 63;
          obf[((size_t)gi * 64 + d) * S + grow] = (bf16_t)v;
        } else {
          const float pv = __shfl_xor(v, 1);  // partner column (d^1), same row
          const int d = gcol & 63, p = d >> 1, hh = gcol >> 6;
          const float c = cs[grow * 32 + p], s = sn[grow * 32 + p];
          float o = (d & 1) ? fmaf(pv, s, v * c) : fmaf(-pv, s, v * c);
          if (mode == 0) o *= 0.125f;  // fold 1/sqrt(64) into q
          obf[((size_t)hh * S + grow) * 64 + d] = (bf16_t)o;
        }
      }
    }
  }
}

// ---------------- flash attention: grid (qblock=32, head=32), 4 waves x 16 q-rows ----------------
__global__ __launch_bounds__(256) void attn_k(
    const bf16_t* __restrict__ qh,   // [32][S][64]
    const bf16_t* __restrict__ kgr,  // [8][S][64]
    const bf16_t* __restrict__ vtg,  // [8][64][S]
    const int* __restrict__ amask,   // [S]
    bf16_t* __restrict__ ao,         // [S][2048]
    const int S) {
  __shared__ bf16_t k_lds[32 * 72];   // 32 keys x 64 d, pad 72
  __shared__ bf16_t vt_lds[64 * 40];  // 64 d x 32 keys, pad 40
  __shared__ bf16_t p_lds[4][16 * 40];
  __shared__ float mb[32];
  const int tid = threadIdx.x, wid = tid >> 6, lane = tid & 63;
  const int fr = lane & 15, kgp = lane >> 4;
  const int qb = blockIdx.x, h = blockIdx.y, g = h >> 2;
  const int q0 = qb * 64 + wid * 16;

  const bf16_t* qbase = qh + ((size_t)h * S + q0 + fr) * 64;
  const bf16x8 qf0 = *(const bf16x8*)&qbase[kgp * 8];
  const bf16x8 qf1 = *(const bf16x8*)&qbase[32 + kgp * 8];

  f32x4 oacc[4];
  float m_[4], l_[4];
  #pragma unroll
  for (int t = 0; t < 4; ++t) oacc[t] = (f32x4){0.f, 0.f, 0.f, 0.f};
  #pragma unroll
  for (int r = 0; r < 4; ++r) { m_[r] = -1e30f; l_[r] = 0.f; }

  const int srow = tid >> 3, ssg = tid & 7;   // K staging: 32 rows x 8 segs
  const int sd = tid >> 2, ssg2 = tid & 3;    // V staging: 64 rows x 4 segs
  const int cmax = 2 * qb + 2;

  for (int c = 0; c < cmax; ++c) {
    const int kc0 = c * 32;
    bf16x8 kv_ = *(const bf16x8*)&kgr[((size_t)g * S + kc0 + srow) * 64 + ssg * 8];
    bf16x8 vv_ = *(const bf16x8*)&vtg[((size_t)g * 64 + sd) * S + kc0 + ssg2 * 8];
    int mv = (tid < 32) ? amask[kc0 + tid] : 1;
    __syncthreads();
    *(bf16x8*)&k_lds[srow * 72 + ssg * 8] = kv_;
    *(bf16x8*)&vt_lds[sd * 40 + ssg2 * 8] = vv_;
    if (tid < 32) mb[tid] = mv ? 0.f : -1e30f;
    __syncthreads();

    if (kc0 <= q0 + 15) {  // wave has at least one valid (causal) key in chunk
      f32x4 sc[2];
      #pragma unroll
      for (int nt = 0; nt < 2; ++nt) {
        const int j = nt * 16 + fr;
        bf16x8 kb0 = *(const bf16x8*)&k_lds[j * 72 + kgp * 8];
        bf16x8 kb1 = *(const bf16x8*)&k_lds[j * 72 + 32 + kgp * 8];
        f32x4 z = (f32x4){0.f, 0.f, 0.f, 0.f};
        z = __builtin_amdgcn_mfma_f32_16x16x32_bf16(qf0, kb0, z, 0, 0, 0);
        z = __builtin_amdgcn_mfma_f32_16x16x32_bf16(qf1, kb1, z, 0, 0, 0);
        sc[nt] = z;
      }
      const float b0 = mb[fr], b1 = mb[16 + fr];
      const bool needmask = (kc0 + 31 > q0);  // any key in chunk can exceed the wave's MIN row
      #pragma unroll
      for (int r = 0; r < 4; ++r) {
        const int irow = q0 + kgp * 4 + r;
        float s0 = sc[0][r] + b0;
        float s1 = sc[1][r] + b1;
        if (needmask) {
          if (kc0 + fr > irow) s0 = -1e30f;
          if (kc0 + 16 + fr > irow) s1 = -1e30f;
        }
        float mx = fmaxf(s0, s1);
        mx = fmaxf(mx, __shfl_xor(mx, 1));
        mx = fmaxf(mx, __shfl_xor(mx, 2));
        mx = fmaxf(mx, __shfl_xor(mx, 4));
        mx = fmaxf(mx, __shfl_xor(mx, 8));
        const float mn = fmaxf(m_[r], mx);
        const float al = exp2f((m_[r] - mn) * LOG2E);
        const float p0 = exp2f((s0 - mn) * LOG2E);
        const float p1 = exp2f((s1 - mn) * LOG2E);
        float ps = p0 + p1;
        ps += __shfl_xor(ps, 1);
        ps += __shfl_xor(ps, 2);
        ps += __shfl_xor(ps, 4);
        ps += __shfl_xor(ps, 8);
        l_[r] = l_[r] * al + ps;
        m_[r] = mn;
        #pragma unroll
        for (int t = 0; t < 4; ++t) oacc[t][r] *= al;
        const int ii = kgp * 4 + r;
        p_lds[wid][ii * 40 + fr]      = (bf16_t)p0;
        p_lds[wid][ii * 40 + 16 + fr] = (bf16_t)p1;
      }
      asm volatile("s_waitcnt lgkmcnt(0)" ::: "memory");
      const bf16x8 pa = *(const bf16x8*)&p_lds[wid][fr * 40 + kgp * 8];
      #pragma unroll
      for (int t = 0; t < 4; ++t) {
        const int j = t * 16 + fr;
        const bf16x8 vb = *(const bf16x8*)&vt_lds[j * 40 + kgp * 8];
        oacc[t] = __builtin_amdgcn_mfma_f32_16x16x32_bf16(pa, vb, oacc[t], 0, 0, 0);
      }
    }
    __syncthreads();
  }

  #pragma unroll
  for (int t = 0; t < 4; ++t) {
    #pragma unroll
    for (int r = 0; r < 4; ++r) {
      const int irow = q0 + kgp * 4 + r;
      const int d = t * 16 + fr;
      const float ov = oacc[t][r] / l_[r];
      ao[(size_t)irow * 2048 + h * 64 + d] = (bf16_t)ov;
    }
  }
}

// ---------------- launcher ----------------
extern "C" void kernel_launch(void* const* d_in, const int* in_sizes, int n_in,
                              void* d_out, int out_size, void* d_ws, size_t ws_size,
                              hipStream_t stream) {
  const float* Q  = (const float*)d_in[0];
  const float* K  = (const float*)d_in[1];
  const float* V  = (const float*)d_in[2];
  const int*   am = (const int*)d_in[3];
  const float* Wq = (const float*)d_in[4];
  const float* Wk = (const float*)d_in[5];
  const float* Wv = (const float*)d_in[6];
  const float* Wo = (const float*)d_in[7];
  const float* bo = (const float*)d_in[8];
  float* out = (float*)d_out;

  const int S = 2048, D = 2048, KV = 512;
  char* w = (char*)d_ws;
  const size_t MB = 1u << 20;
  bf16_t* Qb  = (bf16_t*)(w + 0 * MB);   // [S][D]
  bf16_t* Kb  = (bf16_t*)(w + 8 * MB);
  bf16_t* Vb  = (bf16_t*)(w + 16 * MB);
  bf16_t* WqT = (bf16_t*)(w + 24 * MB);  // [D][D]
  bf16_t* WkT = (bf16_t*)(w + 32 * MB);  // [KV][D]
  bf16_t* WvT = (bf16_t*)(w + 34 * MB);
  bf16_t* WoT = (bf16_t*)(w + 36 * MB);  // [D][D]
  bf16_t* qh  = (bf16_t*)(w + 44 * MB);  // [32][S][64]
  bf16_t* kgr = (bf16_t*)(w + 52 * MB);  // [8][S][64]
  bf16_t* vtg = (bf16_t*)(w + 54 * MB);  // [8][64][S]
  bf16_t* ao  = (bf16_t*)(w + 56 * MB);  // [S][D]
  float*  cs  = (float*)(w + 64 * MB);   // [S][32]
  float*  sn  = (float*)(w + 64 * MB + 256 * 1024);

  rope_table_k<<<256, 256, 0, stream>>>(cs, sn, S);
  cast_bf16_k<<<4096, 256, 0, stream>>>(Q, Qb, S * D / 4);
  cast_bf16_k<<<4096, 256, 0, stream>>>(K, Kb, S * D / 4);
  cast_bf16_k<<<4096, 256, 0, stream>>>(V, Vb, S * D / 4);
  dim3 tb(32, 8);
  transpose_cast_k<<<dim3(64, 64), tb, 0, stream>>>(Wq, WqT, D, D);
  transpose_cast_k<<<dim3(16, 64), tb, 0, stream>>>(Wk, WkT, D, KV);
  transpose_cast_k<<<dim3(16, 64), tb, 0, stream>>>(Wv, WvT, D, KV);
  transpose_cast_k<<<dim3(64, 64), tb, 0, stream>>>(Wo, WoT, D, D);

  gemm_bf16_k<<<dim3(16, 16), 256, 0, stream>>>(Qb, WqT, S, D, D, 0, cs, sn, qh, nullptr, nullptr, S);
  gemm_bf16_k<<<dim3(4, 16), 256, 0, stream>>>(Kb, WkT, S, KV, D, 1, cs, sn, kgr, nullptr, nullptr, S);
  gemm_bf16_k<<<dim3(4, 16), 256, 0, stream>>>(Vb, WvT, S, KV, D, 2, cs, sn, vtg, nullptr, nullptr, S);

  attn_k<<<dim3(32, 32), 256, 0, stream>>>(qh, kgr, vtg, am, ao, S);

  gemm_bf16_k<<<dim3(16, 16), 256, 0, stream>>>(ao, WoT, S, D, D, 3, nullptr, nullptr, nullptr, out, bo, S);
}

// Round 4
// 372.202 us; speedup vs baseline: 1.1597x; 1.1597x over previous
//
#include <hip/hip_runtime.h>

typedef __bf16 bf16_t;
typedef __bf16 bf16x8 __attribute__((ext_vector_type(8)));
typedef __bf16 bf16x4 __attribute__((ext_vector_type(4)));
typedef __bf16 bf16x2 __attribute__((ext_vector_type(2)));
typedef float  f32x4  __attribute__((ext_vector_type(4)));

#define LOG2E 1.44269504088896340736f

// ---------------- RoPE table: cos/sin [S][32] ----------------
__global__ __launch_bounds__(256) void rope_table_k(float* __restrict__ cs,
                                                    float* __restrict__ sn, int S) {
  int i = blockIdx.x * 256 + threadIdx.x;
  if (i >= S * 32) return;
  int s = i >> 5, j = i & 31;
  float theta = powf(10000.0f, -(float)j * (1.0f / 32.0f));
  float a = (float)s * theta;
  cs[i] = cosf(a);
  sn[i] = sinf(a);
}

// ---------------- f32 -> bf16 cast (x4 vectorized) ----------------
__global__ __launch_bounds__(256) void cast_bf16_k(const float* __restrict__ in,
                                                   bf16_t* __restrict__ out, int n4) {
  int i = blockIdx.x * 256 + threadIdx.x;
  if (i >= n4) return;
  const float4 v = ((const float4*)in)[i];
  bf16x4 o;
  o[0] = (bf16_t)v.x; o[1] = (bf16_t)v.y; o[2] = (bf16_t)v.z; o[3] = (bf16_t)v.w;
  ((bf16x4*)out)[i] = o;
}

// ---------------- f32 (R x C) -> bf16 transpose (C x R) ----------------
__global__ void transpose_cast_k(const float* __restrict__ in, bf16_t* __restrict__ out,
                                 int R, int C) {
  __shared__ float tile[32][33];
  int c0 = blockIdx.x * 32, r0 = blockIdx.y * 32;
  int tx = threadIdx.x, ty = threadIdx.y;  // (32,8)
  #pragma unroll
  for (int k = 0; k < 32; k += 8)
    tile[ty + k][tx] = in[(size_t)(r0 + ty + k) * C + c0 + tx];
  __syncthreads();
  #pragma unroll
  for (int k = 0; k < 32; k += 8)
    out[(size_t)(c0 + ty + k) * R + r0 + tx] = (bf16_t)tile[tx][ty + k];
}

// ---------------- bf16 GEMM: C = A(MxK) * BT(NxK)^T, fused epilogues ----------------
// mode 0: RoPE + 0.125 scale, store bf16 q[h][s][64]   (h = col/64)
// mode 1: RoPE,               store bf16 k[g][s][64]
// mode 2: plain,              store bf16 vT[g][64][s]  (transposed)
// mode 3: + bias,             store f32  out[s][col]
__global__ __launch_bounds__(256) void gemm_bf16_k(
    const bf16_t* __restrict__ A, const bf16_t* __restrict__ BT,
    const int M, const int N, const int K, const int mode,
    const float* __restrict__ cs, const float* __restrict__ sn,
    bf16_t* __restrict__ obf, float* __restrict__ ofp,
    const float* __restrict__ bias, const int S) {
  __shared__ bf16_t a_lds[128][40];
  __shared__ bf16_t b_lds[128][40];
  const int tid = threadIdx.x;
  const int wid = tid >> 6, lane = tid & 63;
  const int fr = lane & 15, kg = lane >> 4;
  const int row0 = blockIdx.y * 128, col0 = blockIdx.x * 128;
  const int wr = (wid >> 1) * 64, wc = (wid & 1) * 64;

  f32x4 acc[4][4];
  #pragma unroll
  for (int i = 0; i < 4; ++i)
    #pragma unroll
    for (int j = 0; j < 4; ++j)
      acc[i][j] = (f32x4){0.f, 0.f, 0.f, 0.f};

  const int r0 = tid >> 2, sg0 = tid & 3;  // chunk 0 (rows 0..63)
  const int r1 = 64 + r0;                  // chunk 1 (rows 64..127)

  for (int kt = 0; kt < K; kt += 32) {
    bf16x8 av0 = *(const bf16x8*)&A [(size_t)(row0 + r0) * K + kt + sg0 * 8];
    bf16x8 av1 = *(const bf16x8*)&A [(size_t)(row0 + r1) * K + kt + sg0 * 8];
    bf16x8 bv0 = *(const bf16x8*)&BT[(size_t)(col0 + r0) * K + kt + sg0 * 8];
    bf16x8 bv1 = *(const bf16x8*)&BT[(size_t)(col0 + r1) * K + kt + sg0 * 8];
    __syncthreads();
    *(bf16x8*)&a_lds[r0][sg0 * 8] = av0;
    *(bf16x8*)&a_lds[r1][sg0 * 8] = av1;
    *(bf16x8*)&b_lds[r0][sg0 * 8] = bv0;
    *(bf16x8*)&b_lds[r1][sg0 * 8] = bv1;
    __syncthreads();
    bf16x8 af[4], bfr[4];
    #pragma unroll
    for (int mi = 0; mi < 4; ++mi) af[mi]  = *(const bf16x8*)&a_lds[wr + mi * 16 + fr][kg * 8];
    #pragma unroll
    for (int ni = 0; ni < 4; ++ni) bfr[ni] = *(const bf16x8*)&b_lds[wc + ni * 16 + fr][kg * 8];
    #pragma unroll
    for (int mi = 0; mi < 4; ++mi)
      #pragma unroll
      for (int ni = 0; ni < 4; ++ni)
        acc[mi][ni] = __builtin_amdgcn_mfma_f32_16x16x32_bf16(af[mi], bfr[ni], acc[mi][ni], 0, 0, 0);
  }

  #pragma unroll
  for (int mi = 0; mi < 4; ++mi) {
    #pragma unroll
    for (int ni = 0; ni < 4; ++ni) {
      #pragma unroll
      for (int r = 0; r < 4; ++r) {
        const int grow = row0 + wr + mi * 16 + kg * 4 + r;  // C row = 4*(lane>>4)+reg
        const int gcol = col0 + wc + ni * 16 + fr;          // C col = lane&15
        float v = acc[mi][ni][r];
        if (mode == 3) {
          ofp[(size_t)grow * N + gcol] = v + bias[gcol];
        } else if (mode == 2) {
          const int gi = gcol >> 6, d = gcol & 63;
          obf[((size_t)gi * 64 + d) * S + grow] = (bf16_t)v;
        } else {
          const float pv = __shfl_xor(v, 1);  // partner column (d^1), same row
          const int d = gcol & 63, p = d >> 1, hh = gcol >> 6;
          const float c = cs[grow * 32 + p], s = sn[grow * 32 + p];
          float o = (d & 1) ? fmaf(pv, s, v * c) : fmaf(-pv, s, v * c);
          if (mode == 0) o *= 0.125f;  // fold 1/sqrt(64) into q
          obf[((size_t)hh * S + grow) * 64 + d] = (bf16_t)o;
        }
      }
    }
  }
}

// ---------------- flash attention v2: swapped operands, KVBLK=64, dbuf, LPT ----------------
// Per block: 64 q-rows (4 waves x 16), one head. grid (32 qb-LPT, 32 heads).
// Swapped QK: sc = mfma(K_frag, Q_frag) -> C col = q (lane&15), row = k_local (4*kgp+r).
// Swapped PV: oacc = mfma(Vt_frag, Pt_frag) -> C col = q (lane&15), row = d_local.
// Softmax state (m, l) is one scalar per lane (its q-row): k-reduce = in-lane + 2 shfl.
__global__ __launch_bounds__(256) void attn_k(
    const bf16_t* __restrict__ qh,   // [32][S][64]
    const bf16_t* __restrict__ kgr,  // [8][S][64]
    const bf16_t* __restrict__ vtg,  // [8][64][S]
    const int* __restrict__ amask,   // [S]
    bf16_t* __restrict__ ao,         // [S][2048]
    const int S) {
  __shared__ bf16_t k_lds[2][64][72];   // [buf][k][d]
  __shared__ bf16_t vt_lds[2][64][72];  // [buf][d][k]
  __shared__ bf16_t p_lds[4][16][72];   // [wave][q][k]
  const int tid = threadIdx.x, wid = tid >> 6, lane = tid & 63;
  const int fr = lane & 15, kgp = lane >> 4;
  const int qb = 31 - blockIdx.x;        // LPT: heaviest blocks dispatch first
  const int h = blockIdx.y, g = h >> 2;
  const int q0 = qb * 64 + wid * 16;
  const int qg = q0 + fr;                // this lane's q-row

  // Q fragment (B operand): col = q0+fr, k-dim = d
  const bf16_t* qbase = qh + ((size_t)h * S + q0 + fr) * 64;
  const bf16x8 qf0 = *(const bf16x8*)&qbase[kgp * 8];
  const bf16x8 qf1 = *(const bf16x8*)&qbase[32 + kgp * 8];

  f32x4 oacc[4];
  #pragma unroll
  for (int t = 0; t < 4; ++t) oacc[t] = (f32x4){0.f, 0.f, 0.f, 0.f};
  float m_ = -1e30f, l_ = 0.f;

  const int srow = tid >> 2;           // 0..63
  const int sseg = (tid & 3) * 8;      // 0,8,16,24

  const bf16_t* kbase = kgr + (size_t)g * S * 64;
  const bf16_t* vbase = vtg + (size_t)g * 64 * S;
  const int cmax = qb + 1;

  // prologue: stage chunk 0
  bf16x8 nk0 = *(const bf16x8*)&kbase[(size_t)srow * 64 + sseg];
  bf16x8 nk1 = *(const bf16x8*)&kbase[(size_t)srow * 64 + 32 + sseg];
  bf16x8 nv0 = *(const bf16x8*)&vbase[(size_t)srow * S + sseg];
  bf16x8 nv1 = *(const bf16x8*)&vbase[(size_t)srow * S + 32 + sseg];
  int mvc = amask[lane];
  *(bf16x8*)&k_lds[0][srow][sseg]       = nk0;
  *(bf16x8*)&k_lds[0][srow][32 + sseg]  = nk1;
  *(bf16x8*)&vt_lds[0][srow][sseg]      = nv0;
  *(bf16x8*)&vt_lds[0][srow][32 + sseg] = nv1;
  __syncthreads();

  int cur = 0;
  for (int c = 0; c < cmax; ++c) {
    const int kc0 = c * 64;
    const unsigned long long pm = __ballot(mvc == 0);  // bit k = pad-masked
    // prefetch next chunk (issue-early; written after compute)
    const bool more = (c + 1 < cmax);
    if (more) {
      const int kc1 = kc0 + 64;
      nk0 = *(const bf16x8*)&kbase[(size_t)(kc1 + srow) * 64 + sseg];
      nk1 = *(const bf16x8*)&kbase[(size_t)(kc1 + srow) * 64 + 32 + sseg];
      nv0 = *(const bf16x8*)&vbase[(size_t)srow * S + kc1 + sseg];
      nv1 = *(const bf16x8*)&vbase[(size_t)srow * S + kc1 + 32 + sseg];
      mvc = amask[kc1 + lane];
    }

    // QK^T (swapped): 4 k-tiles of 16
    f32x4 sc[4];
    #pragma unroll
    for (int a = 0; a < 4; ++a) {
      const bf16x8 ka0 = *(const bf16x8*)&k_lds[cur][a * 16 + fr][kgp * 8];
      const bf16x8 ka1 = *(const bf16x8*)&k_lds[cur][a * 16 + fr][32 + kgp * 8];
      f32x4 z = (f32x4){0.f, 0.f, 0.f, 0.f};
      z = __builtin_amdgcn_mfma_f32_16x16x32_bf16(ka0, qf0, z, 0, 0, 0);
      z = __builtin_amdgcn_mfma_f32_16x16x32_bf16(ka1, qf1, z, 0, 0, 0);
      sc[a] = z;
    }

    // mask + online softmax (per-lane scalar state)
    float smax = -1e30f;
    #pragma unroll
    for (int a = 0; a < 4; ++a)
      #pragma unroll
      for (int r = 0; r < 4; ++r) {
        const int kl = a * 16 + 4 * kgp + r;
        const bool dead = (kc0 + kl > qg) || ((pm >> kl) & 1);
        sc[a][r] = dead ? -1e30f : sc[a][r];
        smax = fmaxf(smax, sc[a][r]);
      }
    smax = fmaxf(smax, __shfl_xor(smax, 16));
    smax = fmaxf(smax, __shfl_xor(smax, 32));
    const float mn = fmaxf(m_, smax);
    const float al = exp2f((m_ - mn) * LOG2E);
    float ps = 0.f;
    #pragma unroll
    for (int a = 0; a < 4; ++a)
      #pragma unroll
      for (int r = 0; r < 4; ++r) {
        const float p = exp2f((sc[a][r] - mn) * LOG2E);
        sc[a][r] = p;
        ps += p;
      }
    ps += __shfl_xor(ps, 16);
    ps += __shfl_xor(ps, 32);
    l_ = l_ * al + ps;
    m_ = mn;
    #pragma unroll
    for (int t = 0; t < 4; ++t)
      #pragma unroll
      for (int r = 0; r < 4; ++r) oacc[t][r] *= al;

    // P -> LDS [q][k] (paired b32 writes), then read back as B-fragment
    #pragma unroll
    for (int a = 0; a < 4; ++a)
      #pragma unroll
      for (int j = 0; j < 2; ++j) {
        bf16x2 w;
        w[0] = (bf16_t)sc[a][2 * j];
        w[1] = (bf16_t)sc[a][2 * j + 1];
        *(bf16x2*)&p_lds[wid][fr][a * 16 + 4 * kgp + 2 * j] = w;
      }
    const bf16x8 pa0 = *(const bf16x8*)&p_lds[wid][fr][kgp * 8];
    const bf16x8 pa1 = *(const bf16x8*)&p_lds[wid][fr][32 + kgp * 8];

    // PV (swapped): 4 d-tiles
    #pragma unroll
    for (int t = 0; t < 4; ++t) {
      const bf16x8 vb0 = *(const bf16x8*)&vt_lds[cur][t * 16 + fr][kgp * 8];
      const bf16x8 vb1 = *(const bf16x8*)&vt_lds[cur][t * 16 + fr][32 + kgp * 8];
      oacc[t] = __builtin_amdgcn_mfma_f32_16x16x32_bf16(vb0, pa0, oacc[t], 0, 0, 0);
      oacc[t] = __builtin_amdgcn_mfma_f32_16x16x32_bf16(vb1, pa1, oacc[t], 0, 0, 0);
    }

    // write-late: stage next chunk into the other buffer
    if (more) {
      *(bf16x8*)&k_lds[cur ^ 1][srow][sseg]       = nk0;
      *(bf16x8*)&k_lds[cur ^ 1][srow][32 + sseg]  = nk1;
      *(bf16x8*)&vt_lds[cur ^ 1][srow][sseg]      = nv0;
      *(bf16x8*)&vt_lds[cur ^ 1][srow][32 + sseg] = nv1;
    }
    __syncthreads();
    cur ^= 1;
  }

  const float inv = 1.0f / l_;
  #pragma unroll
  for (int t = 0; t < 4; ++t) {
    bf16x4 o4;
    #pragma unroll
    for (int r = 0; r < 4; ++r) o4[r] = (bf16_t)(oacc[t][r] * inv);
    *(bf16x4*)&ao[(size_t)(q0 + fr) * 2048 + h * 64 + t * 16 + 4 * kgp] = o4;
  }
}

// ---------------- launcher ----------------
extern "C" void kernel_launch(void* const* d_in, const int* in_sizes, int n_in,
                              void* d_out, int out_size, void* d_ws, size_t ws_size,
                              hipStream_t stream) {
  const float* Q  = (const float*)d_in[0];
  const float* K  = (const float*)d_in[1];
  const float* V  = (const float*)d_in[2];
  const int*   am = (const int*)d_in[3];
  const float* Wq = (const float*)d_in[4];
  const float* Wk = (const float*)d_in[5];
  const float* Wv = (const float*)d_in[6];
  const float* Wo = (const float*)d_in[7];
  const float* bo = (const float*)d_in[8];
  float* out = (float*)d_out;

  const int S = 2048, D = 2048, KV = 512;
  char* w = (char*)d_ws;
  const size_t MB = 1u << 20;
  bf16_t* Qb  = (bf16_t*)(w + 0 * MB);   // [S][D]
  bf16_t* Kb  = (bf16_t*)(w + 8 * MB);
  bf16_t* Vb  = (bf16_t*)(w + 16 * MB);
  bf16_t* WqT = (bf16_t*)(w + 24 * MB);  // [D][D]
  bf16_t* WkT = (bf16_t*)(w + 32 * MB);  // [KV][D]
  bf16_t* WvT = (bf16_t*)(w + 34 * MB);
  bf16_t* WoT = (bf16_t*)(w + 36 * MB);  // [D][D]
  bf16_t* qh  = (bf16_t*)(w + 44 * MB);  // [32][S][64]
  bf16_t* kgr = (bf16_t*)(w + 52 * MB);  // [8][S][64]
  bf16_t* vtg = (bf16_t*)(w + 54 * MB);  // [8][64][S]
  bf16_t* ao  = (bf16_t*)(w + 56 * MB);  // [S][D]
  float*  cs  = (float*)(w + 64 * MB);   // [S][32]
  float*  sn  = (float*)(w + 64 * MB + 256 * 1024);

  rope_table_k<<<256, 256, 0, stream>>>(cs, sn, S);
  cast_bf16_k<<<4096, 256, 0, stream>>>(Q, Qb, S * D / 4);
  cast_bf16_k<<<4096, 256, 0, stream>>>(K, Kb, S * D / 4);
  cast_bf16_k<<<4096, 256, 0, stream>>>(V, Vb, S * D / 4);
  dim3 tb(32, 8);
  transpose_cast_k<<<dim3(64, 64), tb, 0, stream>>>(Wq, WqT, D, D);
  transpose_cast_k<<<dim3(16, 64), tb, 0, stream>>>(Wk, WkT, D, KV);
  transpose_cast_k<<<dim3(16, 64), tb, 0, stream>>>(Wv, WvT, D, KV);
  transpose_cast_k<<<dim3(64, 64), tb, 0, stream>>>(Wo, WoT, D, D);

  gemm_bf16_k<<<dim3(16, 16), 256, 0, stream>>>(Qb, WqT, S, D, D, 0, cs, sn, qh, nullptr, nullptr, S);
  gemm_bf16_k<<<dim3(4, 16), 256, 0, stream>>>(Kb, WkT, S, KV, D, 1, cs, sn, kgr, nullptr, nullptr, S);
  gemm_bf16_k<<<dim3(4, 16), 256, 0, stream>>>(Vb, WvT, S, KV, D, 2, cs, sn, vtg, nullptr, nullptr, S);

  attn_k<<<dim3(32, 32), 256, 0, stream>>>(qh, kgr, vtg, am, ao, S);

  gemm_bf16_k<<<dim3(16, 16), 256, 0, stream>>>(ao, WoT, S, D, D, 3, nullptr, nullptr, nullptr, out, bo, S);
}

// Round 6
// 254.954 us; speedup vs baseline: 1.6930x; 1.4599x over previous
//
#include <hip/hip_runtime.h>

typedef __bf16 bf16_t;
typedef __bf16 bf16x8 __attribute__((ext_vector_type(8)));
typedef __bf16 bf16x4 __attribute__((ext_vector_type(4)));
typedef __bf16 bf16x2 __attribute__((ext_vector_type(2)));
typedef float  f32x4  __attribute__((ext_vector_type(4)));

#define LOG2E 1.44269504088896340736f

// ---------------- RoPE table: cos/sin [S][32] ----------------
__global__ __launch_bounds__(256) void rope_table_k(float* __restrict__ cs,
                                                    float* __restrict__ sn, int S) {
  int i = blockIdx.x * 256 + threadIdx.x;
  if (i >= S * 32) return;
  int s = i >> 5, j = i & 31;
  float theta = powf(10000.0f, -(float)j * (1.0f / 32.0f));
  float a = (float)s * theta;
  cs[i] = cosf(a);
  sn[i] = sinf(a);
}

// ---------------- f32 -> bf16 cast (x4 vectorized) ----------------
__global__ __launch_bounds__(256) void cast_bf16_k(const float* __restrict__ in,
                                                   bf16_t* __restrict__ out, int n4) {
  int i = blockIdx.x * 256 + threadIdx.x;
  if (i >= n4) return;
  const float4 v = ((const float4*)in)[i];
  bf16x4 o;
  o[0] = (bf16_t)v.x; o[1] = (bf16_t)v.y; o[2] = (bf16_t)v.z; o[3] = (bf16_t)v.w;
  ((bf16x4*)out)[i] = o;
}

// ---------------- f32 (R x C) -> bf16 transpose (C x R) ----------------
__global__ void transpose_cast_k(const float* __restrict__ in, bf16_t* __restrict__ out,
                                 int R, int C) {
  __shared__ float tile[32][33];
  int c0 = blockIdx.x * 32, r0 = blockIdx.y * 32;
  int tx = threadIdx.x, ty = threadIdx.y;  // (32,8)
  #pragma unroll
  for (int k = 0; k < 32; k += 8)
    tile[ty + k][tx] = in[(size_t)(r0 + ty + k) * C + c0 + tx];
  __syncthreads();
  #pragma unroll
  for (int k = 0; k < 32; k += 8)
    out[(size_t)(c0 + ty + k) * R + r0 + tx] = (bf16_t)tile[tx][ty + k];
}

// ---------------- bf16 GEMM: C = A(MxK) * BT(NxK)^T, fused epilogues ----------------
// mode 0: RoPE + 0.125*log2e scale, store bf16 q[h][s][64]
// mode 1: RoPE,               store bf16 k[g][s][64]
// mode 2: plain,              store bf16 vT[g][64][s]
// mode 3: + bias,             store f32  out[s][col]
// mode 4: dual KV: blockIdx.x<4 -> mode1 (A, BT -> obf), else mode2 (A2, BT2 -> (bf16*)ofp)
__global__ __launch_bounds__(256) void gemm_bf16_k(
    const bf16_t* __restrict__ A, const bf16_t* __restrict__ A2,
    const bf16_t* __restrict__ BT, const bf16_t* __restrict__ BT2,
    const int M, const int N, const int K, const int mode,
    const float* __restrict__ cs, const float* __restrict__ sn,
    bf16_t* __restrict__ obf, float* __restrict__ ofp,
    const float* __restrict__ bias, const int S) {
  __shared__ bf16_t a_lds[128][40];
  __shared__ bf16_t b_lds[128][40];
  const int tid = threadIdx.x;
  const int wid = tid >> 6, lane = tid & 63;
  const int fr = lane & 15, kg = lane >> 4;
  const bool isV = (mode == 4) && (blockIdx.x >= 4);
  const int emode = (mode == 4) ? (isV ? 2 : 1) : mode;
  const bf16_t* Ap = isV ? A2 : A;       // <-- the round-5 bug: V-proj must read V input
  const bf16_t* Bp = isV ? BT2 : BT;
  bf16_t* op = isV ? (bf16_t*)ofp : obf;
  const int row0 = blockIdx.y * 128;
  const int col0 = ((mode == 4) ? (blockIdx.x & 3) : blockIdx.x) * 128;
  const int wr = (wid >> 1) * 64, wc = (wid & 1) * 64;

  f32x4 acc[4][4];
  #pragma unroll
  for (int i = 0; i < 4; ++i)
    #pragma unroll
    for (int j = 0; j < 4; ++j)
      acc[i][j] = (f32x4){0.f, 0.f, 0.f, 0.f};

  const int r0 = tid >> 2, sg0 = tid & 3;
  const int r1 = 64 + r0;

  for (int kt = 0; kt < K; kt += 32) {
    bf16x8 av0 = *(const bf16x8*)&Ap[(size_t)(row0 + r0) * K + kt + sg0 * 8];
    bf16x8 av1 = *(const bf16x8*)&Ap[(size_t)(row0 + r1) * K + kt + sg0 * 8];
    bf16x8 bv0 = *(const bf16x8*)&Bp[(size_t)(col0 + r0) * K + kt + sg0 * 8];
    bf16x8 bv1 = *(const bf16x8*)&Bp[(size_t)(col0 + r1) * K + kt + sg0 * 8];
    __syncthreads();
    *(bf16x8*)&a_lds[r0][sg0 * 8] = av0;
    *(bf16x8*)&a_lds[r1][sg0 * 8] = av1;
    *(bf16x8*)&b_lds[r0][sg0 * 8] = bv0;
    *(bf16x8*)&b_lds[r1][sg0 * 8] = bv1;
    __syncthreads();
    bf16x8 af[4], bfr[4];
    #pragma unroll
    for (int mi = 0; mi < 4; ++mi) af[mi]  = *(const bf16x8*)&a_lds[wr + mi * 16 + fr][kg * 8];
    #pragma unroll
    for (int ni = 0; ni < 4; ++ni) bfr[ni] = *(const bf16x8*)&b_lds[wc + ni * 16 + fr][kg * 8];
    #pragma unroll
    for (int mi = 0; mi < 4; ++mi)
      #pragma unroll
      for (int ni = 0; ni < 4; ++ni)
        acc[mi][ni] = __builtin_amdgcn_mfma_f32_16x16x32_bf16(af[mi], bfr[ni], acc[mi][ni], 0, 0, 0);
  }

  #pragma unroll
  for (int mi = 0; mi < 4; ++mi) {
    #pragma unroll
    for (int ni = 0; ni < 4; ++ni) {
      #pragma unroll
      for (int r = 0; r < 4; ++r) {
        const int grow = row0 + wr + mi * 16 + kg * 4 + r;
        const int gcol = col0 + wc + ni * 16 + fr;
        float v = acc[mi][ni][r];
        if (emode == 3) {
          ofp[(size_t)grow * N + gcol] = v + bias[gcol];
        } else if (emode == 2) {
          const int gi = gcol >> 6, d = gcol & 63;
          op[((size_t)gi * 64 + d) * S + grow] = (bf16_t)v;
        } else {
          const float pv = __shfl_xor(v, 1);
          const int d = gcol & 63, p = d >> 1, hh = gcol >> 6;
          const float c = cs[grow * 32 + p], s = sn[grow * 32 + p];
          float o = (d & 1) ? fmaf(pv, s, v * c) : fmaf(-pv, s, v * c);
          if (emode == 0) o *= 0.125f * LOG2E;  // fold 1/sqrt(64) and log2(e) into q
          op[((size_t)hh * S + grow) * 64 + d] = (bf16_t)o;
        }
      }
    }
  }
}

// XOR-swizzled LDS index (T2): row stride 64 bf16 (128B), 16B chunk c^(row&7).
__device__ __forceinline__ int swz8(int r, int c) { return r * 64 + (((c) ^ (r & 7)) << 3); }

// ---------------- flash attention v3: single-buf + XOR swizzle + true LPT ----------------
// grid (32 heads /*fast*/, 32 qb-slots): qb = 31 - blockIdx.y so heavy blocks dispatch first.
// Swapped QK/PV: C col = q (lane&15); softmax state per-lane scalar.
__global__ __launch_bounds__(256) void attn_k(
    const bf16_t* __restrict__ qh,   // [32][S][64], pre-scaled by 0.125*log2e
    const bf16_t* __restrict__ kgr,  // [8][S][64]
    const bf16_t* __restrict__ vtg,  // [8][64][S]
    const int* __restrict__ amask,   // [S]
    bf16_t* __restrict__ ao,         // [S][2048]
    const int S) {
  __shared__ bf16_t k_lds[64 * 64];
  __shared__ bf16_t vt_lds[64 * 64];
  __shared__ bf16_t p_lds[4][16 * 64];
  const int tid = threadIdx.x, wid = tid >> 6, lane = tid & 63;
  const int fr = lane & 15, kgp = lane >> 4;
  const int h = blockIdx.x, g = h >> 2;
  const int qb = 31 - blockIdx.y;      // LPT: heavy blocks first in dispatch order
  const int q0 = qb * 64 + wid * 16;
  const int qg = q0 + fr;

  const bf16_t* qbase = qh + ((size_t)h * S + q0 + fr) * 64;
  const bf16x8 qf0 = *(const bf16x8*)&qbase[kgp * 8];
  const bf16x8 qf1 = *(const bf16x8*)&qbase[32 + kgp * 8];

  f32x4 oacc[4];
  #pragma unroll
  for (int t = 0; t < 4; ++t) oacc[t] = (f32x4){0.f, 0.f, 0.f, 0.f};
  float m_ = -1e30f, l_ = 0.f;

  const int srow = tid >> 2, sc4 = tid & 3;  // staging: row, 16B-chunk
  const bf16_t* kbase = kgr + (size_t)g * S * 64;
  const bf16_t* vbase = vtg + (size_t)g * 64 * S;
  const int cmax = qb + 1;

  // prologue: stage chunk 0 (swizzled)
  bf16x8 nk0 = *(const bf16x8*)&kbase[(size_t)srow * 64 + sc4 * 8];
  bf16x8 nk1 = *(const bf16x8*)&kbase[(size_t)srow * 64 + 32 + sc4 * 8];
  bf16x8 nv0 = *(const bf16x8*)&vbase[(size_t)srow * S + sc4 * 8];
  bf16x8 nv1 = *(const bf16x8*)&vbase[(size_t)srow * S + 32 + sc4 * 8];
  int mvc = amask[lane];
  *(bf16x8*)&k_lds[swz8(srow, sc4)]      = nk0;
  *(bf16x8*)&k_lds[swz8(srow, 4 + sc4)]  = nk1;
  *(bf16x8*)&vt_lds[swz8(srow, sc4)]     = nv0;
  *(bf16x8*)&vt_lds[swz8(srow, 4 + sc4)] = nv1;
  __syncthreads();

  for (int c = 0; c < cmax; ++c) {
    const int kc0 = c * 64;
    const unsigned long long pm = __ballot(mvc == 0);
    const bool more = (c + 1 < cmax);
    if (more) {  // issue-early prefetch (written after compute)
      const int kc1 = kc0 + 64;
      nk0 = *(const bf16x8*)&kbase[(size_t)(kc1 + srow) * 64 + sc4 * 8];
      nk1 = *(const bf16x8*)&kbase[(size_t)(kc1 + srow) * 64 + 32 + sc4 * 8];
      nv0 = *(const bf16x8*)&vbase[(size_t)srow * S + kc1 + sc4 * 8];
      nv1 = *(const bf16x8*)&vbase[(size_t)srow * S + kc1 + 32 + sc4 * 8];
      mvc = amask[kc1 + lane];
    }

    // QK^T (swapped): scores in log2 domain (q pre-scaled)
    f32x4 sc[4];
    #pragma unroll
    for (int a = 0; a < 4; ++a) {
      const bf16x8 ka0 = *(const bf16x8*)&k_lds[swz8(a * 16 + fr, kgp)];
      const bf16x8 ka1 = *(const bf16x8*)&k_lds[swz8(a * 16 + fr, 4 + kgp)];
      f32x4 z = (f32x4){0.f, 0.f, 0.f, 0.f};
      z = __builtin_amdgcn_mfma_f32_16x16x32_bf16(ka0, qf0, z, 0, 0, 0);
      z = __builtin_amdgcn_mfma_f32_16x16x32_bf16(ka1, qf1, z, 0, 0, 0);
      sc[a] = z;
    }

    // masks: causal only on the diagonal chunk; pad only if any bit set (wave-uniform)
    if (c == qb) {
      #pragma unroll
      for (int a = 0; a < 4; ++a)
        #pragma unroll
        for (int r = 0; r < 4; ++r) {
          const int kl = a * 16 + 4 * kgp + r;
          if (kc0 + kl > qg) sc[a][r] = -1e30f;
        }
    }
    if (pm) {
      #pragma unroll
      for (int a = 0; a < 4; ++a)
        #pragma unroll
        for (int r = 0; r < 4; ++r) {
          const int kl = a * 16 + 4 * kgp + r;
          if ((pm >> kl) & 1) sc[a][r] = -1e30f;
        }
    }

    // online softmax (log2 domain), per-lane state, 2+2 cross-lane ops
    float smax = sc[0][0];
    #pragma unroll
    for (int a = 0; a < 4; ++a)
      #pragma unroll
      for (int r = 0; r < 4; ++r) smax = fmaxf(smax, sc[a][r]);
    smax = fmaxf(smax, __shfl_xor(smax, 16));
    smax = fmaxf(smax, __shfl_xor(smax, 32));
    const float mn = fmaxf(m_, smax);
    const float al = exp2f(m_ - mn);
    float ps = 0.f;
    #pragma unroll
    for (int a = 0; a < 4; ++a)
      #pragma unroll
      for (int r = 0; r < 4; ++r) {
        const float p = exp2f(sc[a][r] - mn);
        sc[a][r] = p;
        ps += p;
      }
    ps += __shfl_xor(ps, 16);
    ps += __shfl_xor(ps, 32);
    l_ = l_ * al + ps;
    m_ = mn;
    #pragma unroll
    for (int t = 0; t < 4; ++t)
      #pragma unroll
      for (int r = 0; r < 4; ++r) oacc[t][r] *= al;

    // P -> LDS (swizzled b32 writes), read back as B-fragment
    #pragma unroll
    for (int a = 0; a < 4; ++a)
      #pragma unroll
      for (int j = 0; j < 2; ++j) {
        bf16x2 w;
        w[0] = (bf16_t)sc[a][2 * j];
        w[1] = (bf16_t)sc[a][2 * j + 1];
        const int off = a * 16 + 4 * kgp + 2 * j;
        *(bf16x2*)&p_lds[wid][fr * 64 + (((off >> 3) ^ (fr & 7)) << 3) + (off & 7)] = w;
      }
    const bf16x8 pa0 = *(const bf16x8*)&p_lds[wid][swz8(fr, kgp)];
    const bf16x8 pa1 = *(const bf16x8*)&p_lds[wid][swz8(fr, 4 + kgp)];

    // PV (swapped)
    #pragma unroll
    for (int t = 0; t < 4; ++t) {
      const bf16x8 vb0 = *(const bf16x8*)&vt_lds[swz8(t * 16 + fr, kgp)];
      const bf16x8 vb1 = *(const bf16x8*)&vt_lds[swz8(t * 16 + fr, 4 + kgp)];
      oacc[t] = __builtin_amdgcn_mfma_f32_16x16x32_bf16(vb0, pa0, oacc[t], 0, 0, 0);
      oacc[t] = __builtin_amdgcn_mfma_f32_16x16x32_bf16(vb1, pa1, oacc[t], 0, 0, 0);
    }

    if (more) {  // write-late into the single buffer
      __syncthreads();
      *(bf16x8*)&k_lds[swz8(srow, sc4)]      = nk0;
      *(bf16x8*)&k_lds[swz8(srow, 4 + sc4)]  = nk1;
      *(bf16x8*)&vt_lds[swz8(srow, sc4)]     = nv0;
      *(bf16x8*)&vt_lds[swz8(srow, 4 + sc4)] = nv1;
      __syncthreads();
    }
  }

  const float inv = 1.0f / l_;
  #pragma unroll
  for (int t = 0; t < 4; ++t) {
    bf16x4 o4;
    #pragma unroll
    for (int r = 0; r < 4; ++r) o4[r] = (bf16_t)(oacc[t][r] * inv);
    *(bf16x4*)&ao[(size_t)(q0 + fr) * 2048 + h * 64 + t * 16 + 4 * kgp] = o4;
  }
}

// ---------------- launcher ----------------
extern "C" void kernel_launch(void* const* d_in, const int* in_sizes, int n_in,
                              void* d_out, int out_size, void* d_ws, size_t ws_size,
                              hipStream_t stream) {
  const float* Q  = (const float*)d_in[0];
  const float* K  = (const float*)d_in[1];
  const float* V  = (const float*)d_in[2];
  const int*   am = (const int*)d_in[3];
  const float* Wq = (const float*)d_in[4];
  const float* Wk = (const float*)d_in[5];
  const float* Wv = (const float*)d_in[6];
  const float* Wo = (const float*)d_in[7];
  const float* bo = (const float*)d_in[8];
  float* out = (float*)d_out;

  const int S = 2048, D = 2048, KV = 512;
  char* w = (char*)d_ws;
  const size_t MB = 1u << 20;
  bf16_t* Qb  = (bf16_t*)(w + 0 * MB);   // [S][D]
  bf16_t* Kb  = (bf16_t*)(w + 8 * MB);
  bf16_t* Vb  = (bf16_t*)(w + 16 * MB);
  bf16_t* WqT = (bf16_t*)(w + 24 * MB);  // [D][D]
  bf16_t* WkT = (bf16_t*)(w + 32 * MB);  // [KV][D]
  bf16_t* WvT = (bf16_t*)(w + 34 * MB);
  bf16_t* WoT = (bf16_t*)(w + 36 * MB);  // [D][D]
  bf16_t* qh  = (bf16_t*)(w + 44 * MB);  // [32][S][64]
  bf16_t* kgr = (bf16_t*)(w + 52 * MB);  // [8][S][64]
  bf16_t* vtg = (bf16_t*)(w + 54 * MB);  // [8][64][S]
  bf16_t* ao  = (bf16_t*)(w + 56 * MB);  // [S][D]
  float*  cs  = (float*)(w + 64 * MB);   // [S][32]
  float*  sn  = (float*)(w + 64 * MB + 256 * 1024);

  rope_table_k<<<256, 256, 0, stream>>>(cs, sn, S);
  cast_bf16_k<<<4096, 256, 0, stream>>>(Q, Qb, S * D / 4);
  cast_bf16_k<<<4096, 256, 0, stream>>>(K, Kb, S * D / 4);
  cast_bf16_k<<<4096, 256, 0, stream>>>(V, Vb, S * D / 4);
  dim3 tb(32, 8);
  transpose_cast_k<<<dim3(64, 64), tb, 0, stream>>>(Wq, WqT, D, D);
  transpose_cast_k<<<dim3(16, 64), tb, 0, stream>>>(Wk, WkT, D, KV);
  transpose_cast_k<<<dim3(16, 64), tb, 0, stream>>>(Wv, WvT, D, KV);
  transpose_cast_k<<<dim3(64, 64), tb, 0, stream>>>(Wo, WoT, D, D);

  gemm_bf16_k<<<dim3(16, 16), 256, 0, stream>>>(Qb, nullptr, WqT, nullptr, S, D, D, 0, cs, sn, qh, nullptr, nullptr, S);
  gemm_bf16_k<<<dim3(8, 16), 256, 0, stream>>>(Kb, Vb, WkT, WvT, S, KV, D, 4, cs, sn, kgr, (float*)vtg, nullptr, S);

  attn_k<<<dim3(32, 32), 256, 0, stream>>>(qh, kgr, vtg, am, ao, S);

  gemm_bf16_k<<<dim3(16, 16), 256, 0, stream>>>(ao, nullptr, WoT, nullptr, S, D, D, 3, nullptr, nullptr, nullptr, out, bo, S);
}

// Round 7
// 167.690 us; speedup vs baseline: 2.5741x; 1.5204x over previous
//
#include <hip/hip_runtime.h>

typedef __bf16 bf16_t;
typedef __bf16 bf16x8 __attribute__((ext_vector_type(8)));
typedef __bf16 bf16x4 __attribute__((ext_vector_type(4)));
typedef __bf16 bf16x2 __attribute__((ext_vector_type(2)));
typedef float  f32x4  __attribute__((ext_vector_type(4)));

#define LOG2E 1.44269504088896340736f

// ---------------- RoPE table: cos/sin [S][32] ----------------
__global__ __launch_bounds__(256) void rope_table_k(float* __restrict__ cs,
                                                    float* __restrict__ sn, int S) {
  int i = blockIdx.x * 256 + threadIdx.x;
  if (i >= S * 32) return;
  int s = i >> 5, j = i & 31;
  float theta = powf(10000.0f, -(float)j * (1.0f / 32.0f));
  float a = (float)s * theta;
  cs[i] = cosf(a);
  sn[i] = sinf(a);
}

// ---------------- f32 (R x C) -> bf16 transpose (C x R) ----------------
__global__ void transpose_cast_k(const float* __restrict__ in, bf16_t* __restrict__ out,
                                 int R, int C) {
  __shared__ float tile[32][33];
  int c0 = blockIdx.x * 32, r0 = blockIdx.y * 32;
  int tx = threadIdx.x, ty = threadIdx.y;  // (32,8)
  #pragma unroll
  for (int k = 0; k < 32; k += 8)
    tile[ty + k][tx] = in[(size_t)(r0 + ty + k) * C + c0 + tx];
  __syncthreads();
  #pragma unroll
  for (int k = 0; k < 32; k += 8)
    out[(size_t)(c0 + ty + k) * R + r0 + tx] = (bf16_t)tile[tx][ty + k];
}

// ---------------- GEMM v2: tile 64(M)x128(N), BK=64, reg prefetch, fused epilogues ----
// AF32=1: A inputs are raw f32 (cast folded in). AF32=0: A is bf16.
// mode 5 (fused QKV, grid.x=24): cb<16 -> Q (emode0), cb<20 -> K (emode1), else V (emode2)
// mode 3 (O-proj, grid.x=N/128): emode3 = +bias, f32 store
// emode 0: RoPE + 0.125*log2e scale -> oq  bf16 [32][S][64]
// emode 1: RoPE                     -> okg bf16 [8][S][64]
// emode 2: plain, transposed        -> ovt bf16 [8][64][S]
// emode 3: + bias                   -> ofp f32  [S][N]
template<int AF32>
__global__ __launch_bounds__(256) void gemm2_k(
    const void* __restrict__ Aq, const void* __restrict__ Ak, const void* __restrict__ Av,
    const bf16_t* __restrict__ Bq, const bf16_t* __restrict__ Bk, const bf16_t* __restrict__ Bv,
    const int K, const int N, const int mode,
    const float* __restrict__ cs, const float* __restrict__ sn,
    bf16_t* __restrict__ oq, bf16_t* __restrict__ okg, bf16_t* __restrict__ ovt,
    float* __restrict__ ofp, const float* __restrict__ bias, const int S) {
  __shared__ bf16_t a_lds[64][72];
  __shared__ bf16_t b_lds[128][72];
  const int tid = threadIdx.x;
  const int wid = tid >> 6, lane = tid & 63;
  const int fr = lane & 15, kg = lane >> 4;

  const int cb = blockIdx.x, rb = blockIdx.y;
  const void* Ap; const bf16_t* Bp; int emode, col0;
  if (mode == 3) { Ap = Aq; Bp = Bq; emode = 3; col0 = cb * 128; }
  else if (cb < 16) { Ap = Aq; Bp = Bq; emode = 0; col0 = cb * 128; }
  else if (cb < 20) { Ap = Ak; Bp = Bk; emode = 1; col0 = (cb - 16) * 128; }
  else              { Ap = Av; Bp = Bv; emode = 2; col0 = (cb - 20) * 128; }
  const int row0 = rb * 64;
  const int wr = (wid >> 1) * 32, wc = (wid & 1) * 64;

  f32x4 acc[2][4];
  #pragma unroll
  for (int i = 0; i < 2; ++i)
    #pragma unroll
    for (int j = 0; j < 4; ++j)
      acc[i][j] = (f32x4){0.f, 0.f, 0.f, 0.f};

  // staging: A 64 rows x 4 segs of 16 elems; B 128 rows x 2 segs of 32 elems
  const int ra = tid >> 2, sa = (tid & 3) * 16;
  const int rbv = tid >> 1, sb = (tid & 1) * 32;

  float4 fa0, fa1, fa2, fa3;   // AF32 path
  bf16x8 a0, a1;               // bf16 path
  bf16x8 b0, b1, b2, b3;

  const float* Af = (const float*)Ap;
  const bf16_t* Ab = (const bf16_t*)Ap;

#define LOADA(kt)                                                              \
  do {                                                                         \
    if (AF32) {                                                                \
      const float* p = &Af[(size_t)(row0 + ra) * K + (kt) + sa];               \
      fa0 = *(const float4*)(p);      fa1 = *(const float4*)(p + 4);           \
      fa2 = *(const float4*)(p + 8);  fa3 = *(const float4*)(p + 12);          \
    } else {                                                                   \
      const bf16_t* p = &Ab[(size_t)(row0 + ra) * K + (kt) + sa];              \
      a0 = *(const bf16x8*)(p); a1 = *(const bf16x8*)(p + 8);                  \
    }                                                                          \
    const bf16_t* q = &Bp[(size_t)(col0 + rbv) * K + (kt) + sb];               \
    b0 = *(const bf16x8*)(q);      b1 = *(const bf16x8*)(q + 8);               \
    b2 = *(const bf16x8*)(q + 16); b3 = *(const bf16x8*)(q + 24);              \
  } while (0)

  LOADA(0);

  for (int kt = 0; kt < K; kt += 64) {
    __syncthreads();
    if (AF32) {
      bf16x8 w0, w1;
      w0[0]=(bf16_t)fa0.x; w0[1]=(bf16_t)fa0.y; w0[2]=(bf16_t)fa0.z; w0[3]=(bf16_t)fa0.w;
      w0[4]=(bf16_t)fa1.x; w0[5]=(bf16_t)fa1.y; w0[6]=(bf16_t)fa1.z; w0[7]=(bf16_t)fa1.w;
      w1[0]=(bf16_t)fa2.x; w1[1]=(bf16_t)fa2.y; w1[2]=(bf16_t)fa2.z; w1[3]=(bf16_t)fa2.w;
      w1[4]=(bf16_t)fa3.x; w1[5]=(bf16_t)fa3.y; w1[6]=(bf16_t)fa3.z; w1[7]=(bf16_t)fa3.w;
      *(bf16x8*)&a_lds[ra][sa] = w0;
      *(bf16x8*)&a_lds[ra][sa + 8] = w1;
    } else {
      *(bf16x8*)&a_lds[ra][sa] = a0;
      *(bf16x8*)&a_lds[ra][sa + 8] = a1;
    }
    *(bf16x8*)&b_lds[rbv][sb]      = b0;
    *(bf16x8*)&b_lds[rbv][sb + 8]  = b1;
    *(bf16x8*)&b_lds[rbv][sb + 16] = b2;
    *(bf16x8*)&b_lds[rbv][sb + 24] = b3;
    __syncthreads();
    if (kt + 64 < K) LOADA(kt + 64);  // prefetch next step; lands during MFMA
    #pragma unroll
    for (int ks = 0; ks < 2; ++ks) {
      bf16x8 af[2], bfr[4];
      #pragma unroll
      for (int mi = 0; mi < 2; ++mi) af[mi]  = *(const bf16x8*)&a_lds[wr + mi * 16 + fr][ks * 32 + kg * 8];
      #pragma unroll
      for (int ni = 0; ni < 4; ++ni) bfr[ni] = *(const bf16x8*)&b_lds[wc + ni * 16 + fr][ks * 32 + kg * 8];
      #pragma unroll
      for (int mi = 0; mi < 2; ++mi)
        #pragma unroll
        for (int ni = 0; ni < 4; ++ni)
          acc[mi][ni] = __builtin_amdgcn_mfma_f32_16x16x32_bf16(af[mi], bfr[ni], acc[mi][ni], 0, 0, 0);
    }
  }
#undef LOADA

  #pragma unroll
  for (int mi = 0; mi < 2; ++mi) {
    #pragma unroll
    for (int ni = 0; ni < 4; ++ni) {
      #pragma unroll
      for (int r = 0; r < 4; ++r) {
        const int grow = row0 + wr + mi * 16 + kg * 4 + r;  // C row = 4*(lane>>4)+reg
        const int gcol = col0 + wc + ni * 16 + fr;          // C col = lane&15
        float v = acc[mi][ni][r];
        if (emode == 3) {
          ofp[(size_t)grow * N + gcol] = v + bias[gcol];
        } else if (emode == 2) {
          const int gi = gcol >> 6, d = gcol & 63;
          ovt[((size_t)gi * 64 + d) * S + grow] = (bf16_t)v;
        } else {
          const float pv = __shfl_xor(v, 1);  // RoPE partner (d^1), same row
          const int d = gcol & 63, p = d >> 1, hh = gcol >> 6;
          const float c = cs[grow * 32 + p], s = sn[grow * 32 + p];
          float o = (d & 1) ? fmaf(pv, s, v * c) : fmaf(-pv, s, v * c);
          if (emode == 0) {
            o *= 0.125f * LOG2E;  // fold 1/sqrt(64) and log2(e) into q
            oq[((size_t)hh * S + grow) * 64 + d] = (bf16_t)o;
          } else {
            okg[((size_t)hh * S + grow) * 64 + d] = (bf16_t)o;
          }
        }
      }
    }
  }
}

// XOR-swizzled LDS index (T2): row stride 64 bf16 (128B), 16B chunk c^(row&7).
__device__ __forceinline__ int swz8(int r, int c) { return r * 64 + (((c) ^ (r & 7)) << 3); }

// ---------------- flash attention v3: single-buf + XOR swizzle + true LPT ----------------
__global__ __launch_bounds__(256) void attn_k(
    const bf16_t* __restrict__ qh,   // [32][S][64], pre-scaled by 0.125*log2e
    const bf16_t* __restrict__ kgr,  // [8][S][64]
    const bf16_t* __restrict__ vtg,  // [8][64][S]
    const int* __restrict__ amask,   // [S]
    bf16_t* __restrict__ ao,         // [S][2048]
    const int S) {
  __shared__ bf16_t k_lds[64 * 64];
  __shared__ bf16_t vt_lds[64 * 64];
  __shared__ bf16_t p_lds[4][16 * 64];
  const int tid = threadIdx.x, wid = tid >> 6, lane = tid & 63;
  const int fr = lane & 15, kgp = lane >> 4;
  const int h = blockIdx.x, g = h >> 2;
  const int qb = 31 - blockIdx.y;      // LPT: heavy blocks first in dispatch order
  const int q0 = qb * 64 + wid * 16;
  const int qg = q0 + fr;

  const bf16_t* qbase = qh + ((size_t)h * S + q0 + fr) * 64;
  const bf16x8 qf0 = *(const bf16x8*)&qbase[kgp * 8];
  const bf16x8 qf1 = *(const bf16x8*)&qbase[32 + kgp * 8];

  f32x4 oacc[4];
  #pragma unroll
  for (int t = 0; t < 4; ++t) oacc[t] = (f32x4){0.f, 0.f, 0.f, 0.f};
  float m_ = -1e30f, l_ = 0.f;

  const int srow = tid >> 2, sc4 = tid & 3;
  const bf16_t* kbase = kgr + (size_t)g * S * 64;
  const bf16_t* vbase = vtg + (size_t)g * 64 * S;
  const int cmax = qb + 1;

  bf16x8 nk0 = *(const bf16x8*)&kbase[(size_t)srow * 64 + sc4 * 8];
  bf16x8 nk1 = *(const bf16x8*)&kbase[(size_t)srow * 64 + 32 + sc4 * 8];
  bf16x8 nv0 = *(const bf16x8*)&vbase[(size_t)srow * S + sc4 * 8];
  bf16x8 nv1 = *(const bf16x8*)&vbase[(size_t)srow * S + 32 + sc4 * 8];
  int mvc = amask[lane];
  *(bf16x8*)&k_lds[swz8(srow, sc4)]      = nk0;
  *(bf16x8*)&k_lds[swz8(srow, 4 + sc4)]  = nk1;
  *(bf16x8*)&vt_lds[swz8(srow, sc4)]     = nv0;
  *(bf16x8*)&vt_lds[swz8(srow, 4 + sc4)] = nv1;
  __syncthreads();

  for (int c = 0; c < cmax; ++c) {
    const int kc0 = c * 64;
    const unsigned long long pm = __ballot(mvc == 0);
    const bool more = (c + 1 < cmax);
    if (more) {  // issue-early prefetch (written after compute)
      const int kc1 = kc0 + 64;
      nk0 = *(const bf16x8*)&kbase[(size_t)(kc1 + srow) * 64 + sc4 * 8];
      nk1 = *(const bf16x8*)&kbase[(size_t)(kc1 + srow) * 64 + 32 + sc4 * 8];
      nv0 = *(const bf16x8*)&vbase[(size_t)srow * S + kc1 + sc4 * 8];
      nv1 = *(const bf16x8*)&vbase[(size_t)srow * S + kc1 + 32 + sc4 * 8];
      mvc = amask[kc1 + lane];
    }

    f32x4 sc[4];
    #pragma unroll
    for (int a = 0; a < 4; ++a) {
      const bf16x8 ka0 = *(const bf16x8*)&k_lds[swz8(a * 16 + fr, kgp)];
      const bf16x8 ka1 = *(const bf16x8*)&k_lds[swz8(a * 16 + fr, 4 + kgp)];
      f32x4 z = (f32x4){0.f, 0.f, 0.f, 0.f};
      z = __builtin_amdgcn_mfma_f32_16x16x32_bf16(ka0, qf0, z, 0, 0, 0);
      z = __builtin_amdgcn_mfma_f32_16x16x32_bf16(ka1, qf1, z, 0, 0, 0);
      sc[a] = z;
    }

    if (c == qb) {
      #pragma unroll
      for (int a = 0; a < 4; ++a)
        #pragma unroll
        for (int r = 0; r < 4; ++r) {
          const int kl = a * 16 + 4 * kgp + r;
          if (kc0 + kl > qg) sc[a][r] = -1e30f;
        }
    }
    if (pm) {
      #pragma unroll
      for (int a = 0; a < 4; ++a)
        #pragma unroll
        for (int r = 0; r < 4; ++r) {
          const int kl = a * 16 + 4 * kgp + r;
          if ((pm >> kl) & 1) sc[a][r] = -1e30f;
        }
    }

    float smax = sc[0][0];
    #pragma unroll
    for (int a = 0; a < 4; ++a)
      #pragma unroll
      for (int r = 0; r < 4; ++r) smax = fmaxf(smax, sc[a][r]);
    smax = fmaxf(smax, __shfl_xor(smax, 16));
    smax = fmaxf(smax, __shfl_xor(smax, 32));
    const float mn = fmaxf(m_, smax);
    const float al = exp2f(m_ - mn);
    float ps = 0.f;
    #pragma unroll
    for (int a = 0; a < 4; ++a)
      #pragma unroll
      for (int r = 0; r < 4; ++r) {
        const float p = exp2f(sc[a][r] - mn);
        sc[a][r] = p;
        ps += p;
      }
    ps += __shfl_xor(ps, 16);
    ps += __shfl_xor(ps, 32);
    l_ = l_ * al + ps;
    m_ = mn;
    #pragma unroll
    for (int t = 0; t < 4; ++t)
      #pragma unroll
      for (int r = 0; r < 4; ++r) oacc[t][r] *= al;

    #pragma unroll
    for (int a = 0; a < 4; ++a)
      #pragma unroll
      for (int j = 0; j < 2; ++j) {
        bf16x2 w;
        w[0] = (bf16_t)sc[a][2 * j];
        w[1] = (bf16_t)sc[a][2 * j + 1];
        const int off = a * 16 + 4 * kgp + 2 * j;
        *(bf16x2*)&p_lds[wid][fr * 64 + (((off >> 3) ^ (fr & 7)) << 3) + (off & 7)] = w;
      }
    const bf16x8 pa0 = *(const bf16x8*)&p_lds[wid][swz8(fr, kgp)];
    const bf16x8 pa1 = *(const bf16x8*)&p_lds[wid][swz8(fr, 4 + kgp)];

    #pragma unroll
    for (int t = 0; t < 4; ++t) {
      const bf16x8 vb0 = *(const bf16x8*)&vt_lds[swz8(t * 16 + fr, kgp)];
      const bf16x8 vb1 = *(const bf16x8*)&vt_lds[swz8(t * 16 + fr, 4 + kgp)];
      oacc[t] = __builtin_amdgcn_mfma_f32_16x16x32_bf16(vb0, pa0, oacc[t], 0, 0, 0);
      oacc[t] = __builtin_amdgcn_mfma_f32_16x16x32_bf16(vb1, pa1, oacc[t], 0, 0, 0);
    }

    if (more) {
      __syncthreads();
      *(bf16x8*)&k_lds[swz8(srow, sc4)]      = nk0;
      *(bf16x8*)&k_lds[swz8(srow, 4 + sc4)]  = nk1;
      *(bf16x8*)&vt_lds[swz8(srow, sc4)]     = nv0;
      *(bf16x8*)&vt_lds[swz8(srow, 4 + sc4)] = nv1;
      __syncthreads();
    }
  }

  const float inv = 1.0f / l_;
  #pragma unroll
  for (int t = 0; t < 4; ++t) {
    bf16x4 o4;
    #pragma unroll
    for (int r = 0; r < 4; ++r) o4[r] = (bf16_t)(oacc[t][r] * inv);
    *(bf16x4*)&ao[(size_t)(q0 + fr) * 2048 + h * 64 + t * 16 + 4 * kgp] = o4;
  }
}

// ---------------- launcher ----------------
extern "C" void kernel_launch(void* const* d_in, const int* in_sizes, int n_in,
                              void* d_out, int out_size, void* d_ws, size_t ws_size,
                              hipStream_t stream) {
  const float* Q  = (const float*)d_in[0];
  const float* K  = (const float*)d_in[1];
  const float* V  = (const float*)d_in[2];
  const int*   am = (const int*)d_in[3];
  const float* Wq = (const float*)d_in[4];
  const float* Wk = (const float*)d_in[5];
  const float* Wv = (const float*)d_in[6];
  const float* Wo = (const float*)d_in[7];
  const float* bo = (const float*)d_in[8];
  float* out = (float*)d_out;

  const int S = 2048, D = 2048, KV = 512;
  char* w = (char*)d_ws;
  const size_t MB = 1u << 20;
  bf16_t* WqT = (bf16_t*)(w + 0 * MB);   // [D][D]
  bf16_t* WkT = (bf16_t*)(w + 8 * MB);   // [KV][D]
  bf16_t* WvT = (bf16_t*)(w + 10 * MB);
  bf16_t* WoT = (bf16_t*)(w + 12 * MB);  // [D][D]
  bf16_t* qh  = (bf16_t*)(w + 20 * MB);  // [32][S][64]
  bf16_t* kgr = (bf16_t*)(w + 28 * MB);  // [8][S][64]
  bf16_t* vtg = (bf16_t*)(w + 30 * MB);  // [8][64][S]
  bf16_t* ao  = (bf16_t*)(w + 32 * MB);  // [S][D]
  float*  cs  = (float*)(w + 40 * MB);   // [S][32]
  float*  sn  = (float*)(w + 40 * MB + 256 * 1024);

  rope_table_k<<<256, 256, 0, stream>>>(cs, sn, S);
  dim3 tb(32, 8);
  transpose_cast_k<<<dim3(64, 64), tb, 0, stream>>>(Wq, WqT, D, D);
  transpose_cast_k<<<dim3(16, 64), tb, 0, stream>>>(Wk, WkT, D, KV);
  transpose_cast_k<<<dim3(16, 64), tb, 0, stream>>>(Wv, WvT, D, KV);
  transpose_cast_k<<<dim3(64, 64), tb, 0, stream>>>(Wo, WoT, D, D);

  // fused Q+K+V projections (f32 A, cast folded in): grid 24x32 = 768 blocks
  gemm2_k<1><<<dim3(24, 32), 256, 0, stream>>>(Q, K, V, WqT, WkT, WvT, D, D, 5,
                                               cs, sn, qh, kgr, vtg, nullptr, nullptr, S);

  attn_k<<<dim3(32, 32), 256, 0, stream>>>(qh, kgr, vtg, am, ao, S);

  // O-proj (bf16 A): grid 16x32 = 512 blocks
  gemm2_k<0><<<dim3(16, 32), 256, 0, stream>>>(ao, nullptr, nullptr, WoT, nullptr, nullptr,
                                               D, D, 3, nullptr, nullptr, nullptr, nullptr,
                                               nullptr, out, bo, S);
}

// Round 8
// 162.118 us; speedup vs baseline: 2.6625x; 1.0344x over previous
//
#include <hip/hip_runtime.h>

typedef __bf16 bf16_t;
typedef __bf16 bf16x8 __attribute__((ext_vector_type(8)));
typedef __bf16 bf16x4 __attribute__((ext_vector_type(4)));
typedef __bf16 bf16x2 __attribute__((ext_vector_type(2)));
typedef float  f32x4  __attribute__((ext_vector_type(4)));

#define LOG2E 1.44269504088896340736f

// ---------------- RoPE table: cos/sin [S][32] ----------------
__global__ __launch_bounds__(256) void rope_table_k(float* __restrict__ cs,
                                                    float* __restrict__ sn, int S) {
  int i = blockIdx.x * 256 + threadIdx.x;
  if (i >= S * 32) return;
  int s = i >> 5, j = i & 31;
  float theta = powf(10000.0f, -(float)j * (1.0f / 32.0f));
  float a = (float)s * theta;
  cs[i] = cosf(a);
  sn[i] = sinf(a);
}

// ---------------- fused f32 -> bf16 cast of Q,K,V (x8 vectorized) ----------------
// grid = 3 * 2048 blocks; n8 = S*D/8 elems8 per input (524288)
__global__ __launch_bounds__(256) void cast3_k(const float* __restrict__ A,
                                               const float* __restrict__ B,
                                               const float* __restrict__ C,
                                               bf16_t* __restrict__ oa,
                                               bf16_t* __restrict__ ob,
                                               bf16_t* __restrict__ oc) {
  const int b = blockIdx.x;
  const float* in; bf16_t* out;
  if (b < 2048) { in = A; out = oa; }
  else if (b < 4096) { in = B; out = ob; }
  else { in = C; out = oc; }
  const int j = (b & 2047) * 256 + threadIdx.x;  // elem8 index
  const float4 v0 = *(const float4*)&in[(size_t)j * 8];
  const float4 v1 = *(const float4*)&in[(size_t)j * 8 + 4];
  bf16x8 o;
  o[0]=(bf16_t)v0.x; o[1]=(bf16_t)v0.y; o[2]=(bf16_t)v0.z; o[3]=(bf16_t)v0.w;
  o[4]=(bf16_t)v1.x; o[5]=(bf16_t)v1.y; o[6]=(bf16_t)v1.z; o[7]=(bf16_t)v1.w;
  *(bf16x8*)&out[(size_t)j * 8] = o;
}

// ---------------- f32 (R x C) -> bf16 transpose (C x R) ----------------
__global__ void transpose_cast_k(const float* __restrict__ in, bf16_t* __restrict__ out,
                                 int R, int C) {
  __shared__ float tile[32][33];
  int c0 = blockIdx.x * 32, r0 = blockIdx.y * 32;
  int tx = threadIdx.x, ty = threadIdx.y;  // (32,8)
  #pragma unroll
  for (int k = 0; k < 32; k += 8)
    tile[ty + k][tx] = in[(size_t)(r0 + ty + k) * C + c0 + tx];
  __syncthreads();
  #pragma unroll
  for (int k = 0; k < 32; k += 8)
    out[(size_t)(c0 + ty + k) * R + r0 + tx] = (bf16_t)tile[tx][ty + k];
}

// bijective XCD-chunk swizzle (m204): consecutive lin ids land on ONE XCD
__device__ __forceinline__ int xcd_swz(int bid, int nb) {
  const int q = nb >> 3, r = nb & 7;
  const int xcd = bid & 7, idx = bid >> 3;
  return (xcd < r ? xcd * (q + 1) : r * (q + 1) + (xcd - r) * q) + idx;
}

// ---------------- GEMM v3: tile 64(M)x128(N), BK=64, bf16 A, reg prefetch, XCD swizzle ----
// mode 5 (fused QKV, ncb=24): cb<16 -> Q (emode0), cb<20 -> K (emode1), else V (emode2)
// mode 3 (O-proj, ncb=16): emode3 = +bias, f32 store
// emode 0: RoPE + 0.125*log2e scale -> oq  bf16 [32][S][64]
// emode 1: RoPE                     -> okg bf16 [8][S][64]
// emode 2: plain, transposed        -> ovt bf16 [8][64][S]
// emode 3: + bias                   -> ofp f32  [S][N]
__global__ __launch_bounds__(256) void gemm2_k(
    const bf16_t* __restrict__ Aq, const bf16_t* __restrict__ Ak, const bf16_t* __restrict__ Av,
    const bf16_t* __restrict__ Bq, const bf16_t* __restrict__ Bk, const bf16_t* __restrict__ Bv,
    const int K, const int N, const int mode,
    const float* __restrict__ cs, const float* __restrict__ sn,
    bf16_t* __restrict__ oq, bf16_t* __restrict__ okg, bf16_t* __restrict__ ovt,
    float* __restrict__ ofp, const float* __restrict__ bias, const int S,
    const int ncb, const int nb) {
  __shared__ bf16_t a_lds[64][72];
  __shared__ bf16_t b_lds[128][72];
  const int tid = threadIdx.x;
  const int wid = tid >> 6, lane = tid & 63;
  const int fr = lane & 15, kg = lane >> 4;

  const int lin = xcd_swz(blockIdx.x, nb);
  const int cb = lin % ncb, rb = lin / ncb;
  const bf16_t* Ap; const bf16_t* Bp; int emode, col0;
  if (mode == 3) { Ap = Aq; Bp = Bq; emode = 3; col0 = cb * 128; }
  else if (cb < 16) { Ap = Aq; Bp = Bq; emode = 0; col0 = cb * 128; }
  else if (cb < 20) { Ap = Ak; Bp = Bk; emode = 1; col0 = (cb - 16) * 128; }
  else              { Ap = Av; Bp = Bv; emode = 2; col0 = (cb - 20) * 128; }
  const int row0 = rb * 64;
  const int wr = (wid >> 1) * 32, wc = (wid & 1) * 64;

  f32x4 acc[2][4];
  #pragma unroll
  for (int i = 0; i < 2; ++i)
    #pragma unroll
    for (int j = 0; j < 4; ++j)
      acc[i][j] = (f32x4){0.f, 0.f, 0.f, 0.f};

  // staging: A 64 rows x 4 segs of 16; B 128 rows x 2 segs of 32
  const int ra = tid >> 2, sa = (tid & 3) * 16;
  const int rbv = tid >> 1, sb = (tid & 1) * 32;

  bf16x8 a0, a1, b0, b1, b2, b3;

#define LOADA(kt)                                                              \
  do {                                                                         \
    const bf16_t* p = &Ap[(size_t)(row0 + ra) * K + (kt) + sa];                \
    a0 = *(const bf16x8*)(p); a1 = *(const bf16x8*)(p + 8);                    \
    const bf16_t* q = &Bp[(size_t)(col0 + rbv) * K + (kt) + sb];               \
    b0 = *(const bf16x8*)(q);      b1 = *(const bf16x8*)(q + 8);               \
    b2 = *(const bf16x8*)(q + 16); b3 = *(const bf16x8*)(q + 24);              \
  } while (0)

  LOADA(0);

  for (int kt = 0; kt < K; kt += 64) {
    __syncthreads();
    *(bf16x8*)&a_lds[ra][sa]      = a0;
    *(bf16x8*)&a_lds[ra][sa + 8]  = a1;
    *(bf16x8*)&b_lds[rbv][sb]      = b0;
    *(bf16x8*)&b_lds[rbv][sb + 8]  = b1;
    *(bf16x8*)&b_lds[rbv][sb + 16] = b2;
    *(bf16x8*)&b_lds[rbv][sb + 24] = b3;
    __syncthreads();
    if (kt + 64 < K) LOADA(kt + 64);  // prefetch next step; lands during MFMA
    #pragma unroll
    for (int ks = 0; ks < 2; ++ks) {
      bf16x8 af[2], bfr[4];
      #pragma unroll
      for (int mi = 0; mi < 2; ++mi) af[mi]  = *(const bf16x8*)&a_lds[wr + mi * 16 + fr][ks * 32 + kg * 8];
      #pragma unroll
      for (int ni = 0; ni < 4; ++ni) bfr[ni] = *(const bf16x8*)&b_lds[wc + ni * 16 + fr][ks * 32 + kg * 8];
      #pragma unroll
      for (int mi = 0; mi < 2; ++mi)
        #pragma unroll
        for (int ni = 0; ni < 4; ++ni)
          acc[mi][ni] = __builtin_amdgcn_mfma_f32_16x16x32_bf16(af[mi], bfr[ni], acc[mi][ni], 0, 0, 0);
    }
  }
#undef LOADA

  #pragma unroll
  for (int mi = 0; mi < 2; ++mi) {
    #pragma unroll
    for (int ni = 0; ni < 4; ++ni) {
      #pragma unroll
      for (int r = 0; r < 4; ++r) {
        const int grow = row0 + wr + mi * 16 + kg * 4 + r;  // C row = 4*(lane>>4)+reg
        const int gcol = col0 + wc + ni * 16 + fr;          // C col = lane&15
        float v = acc[mi][ni][r];
        if (emode == 3) {
          ofp[(size_t)grow * N + gcol] = v + bias[gcol];
        } else if (emode == 2) {
          const int gi = gcol >> 6, d = gcol & 63;
          ovt[((size_t)gi * 64 + d) * S + grow] = (bf16_t)v;
        } else {
          const float pv = __shfl_xor(v, 1);  // RoPE partner (d^1), same row
          const int d = gcol & 63, p = d >> 1, hh = gcol >> 6;
          const float c = cs[grow * 32 + p], s = sn[grow * 32 + p];
          float o = (d & 1) ? fmaf(pv, s, v * c) : fmaf(-pv, s, v * c);
          if (emode == 0) {
            o *= 0.125f * LOG2E;  // fold 1/sqrt(64) and log2(e) into q
            oq[((size_t)hh * S + grow) * 64 + d] = (bf16_t)o;
          } else {
            okg[((size_t)hh * S + grow) * 64 + d] = (bf16_t)o;
          }
        }
      }
    }
  }
}

// XOR-swizzled LDS index (T2): row stride 64 bf16 (128B), 16B chunk c^(row&7).
__device__ __forceinline__ int swz8(int r, int c) { return r * 64 + (((c) ^ (r & 7)) << 3); }

// ---------------- flash attention v3: single-buf + XOR swizzle + true LPT ----------------
__global__ __launch_bounds__(256) void attn_k(
    const bf16_t* __restrict__ qh,   // [32][S][64], pre-scaled by 0.125*log2e
    const bf16_t* __restrict__ kgr,  // [8][S][64]
    const bf16_t* __restrict__ vtg,  // [8][64][S]
    const int* __restrict__ amask,   // [S]
    bf16_t* __restrict__ ao,         // [S][2048]
    const int S) {
  __shared__ bf16_t k_lds[64 * 64];
  __shared__ bf16_t vt_lds[64 * 64];
  __shared__ bf16_t p_lds[4][16 * 64];
  const int tid = threadIdx.x, wid = tid >> 6, lane = tid & 63;
  const int fr = lane & 15, kgp = lane >> 4;
  const int h = blockIdx.x, g = h >> 2;
  const int qb = 31 - blockIdx.y;      // LPT: heavy blocks first in dispatch order
  const int q0 = qb * 64 + wid * 16;
  const int qg = q0 + fr;

  const bf16_t* qbase = qh + ((size_t)h * S + q0 + fr) * 64;
  const bf16x8 qf0 = *(const bf16x8*)&qbase[kgp * 8];
  const bf16x8 qf1 = *(const bf16x8*)&qbase[32 + kgp * 8];

  f32x4 oacc[4];
  #pragma unroll
  for (int t = 0; t < 4; ++t) oacc[t] = (f32x4){0.f, 0.f, 0.f, 0.f};
  float m_ = -1e30f, l_ = 0.f;

  const int srow = tid >> 2, sc4 = tid & 3;
  const bf16_t* kbase = kgr + (size_t)g * S * 64;
  const bf16_t* vbase = vtg + (size_t)g * 64 * S;
  const int cmax = qb + 1;

  bf16x8 nk0 = *(const bf16x8*)&kbase[(size_t)srow * 64 + sc4 * 8];
  bf16x8 nk1 = *(const bf16x8*)&kbase[(size_t)srow * 64 + 32 + sc4 * 8];
  bf16x8 nv0 = *(const bf16x8*)&vbase[(size_t)srow * S + sc4 * 8];
  bf16x8 nv1 = *(const bf16x8*)&vbase[(size_t)srow * S + 32 + sc4 * 8];
  int mvc = amask[lane];
  *(bf16x8*)&k_lds[swz8(srow, sc4)]      = nk0;
  *(bf16x8*)&k_lds[swz8(srow, 4 + sc4)]  = nk1;
  *(bf16x8*)&vt_lds[swz8(srow, sc4)]     = nv0;
  *(bf16x8*)&vt_lds[swz8(srow, 4 + sc4)] = nv1;
  __syncthreads();

  for (int c = 0; c < cmax; ++c) {
    const int kc0 = c * 64;
    const unsigned long long pm = __ballot(mvc == 0);
    const bool more = (c + 1 < cmax);
    if (more) {  // issue-early prefetch (written after compute)
      const int kc1 = kc0 + 64;
      nk0 = *(const bf16x8*)&kbase[(size_t)(kc1 + srow) * 64 + sc4 * 8];
      nk1 = *(const bf16x8*)&kbase[(size_t)(kc1 + srow) * 64 + 32 + sc4 * 8];
      nv0 = *(const bf16x8*)&vbase[(size_t)srow * S + kc1 + sc4 * 8];
      nv1 = *(const bf16x8*)&vbase[(size_t)srow * S + kc1 + 32 + sc4 * 8];
      mvc = amask[kc1 + lane];
    }

    f32x4 sc[4];
    #pragma unroll
    for (int a = 0; a < 4; ++a) {
      const bf16x8 ka0 = *(const bf16x8*)&k_lds[swz8(a * 16 + fr, kgp)];
      const bf16x8 ka1 = *(const bf16x8*)&k_lds[swz8(a * 16 + fr, 4 + kgp)];
      f32x4 z = (f32x4){0.f, 0.f, 0.f, 0.f};
      z = __builtin_amdgcn_mfma_f32_16x16x32_bf16(ka0, qf0, z, 0, 0, 0);
      z = __builtin_amdgcn_mfma_f32_16x16x32_bf16(ka1, qf1, z, 0, 0, 0);
      sc[a] = z;
    }

    if (c == qb) {
      #pragma unroll
      for (int a = 0; a < 4; ++a)
        #pragma unroll
        for (int r = 0; r < 4; ++r) {
          const int kl = a * 16 + 4 * kgp + r;
          if (kc0 + kl > qg) sc[a][r] = -1e30f;
        }
    }
    if (pm) {
      #pragma unroll
      for (int a = 0; a < 4; ++a)
        #pragma unroll
        for (int r = 0; r < 4; ++r) {
          const int kl = a * 16 + 4 * kgp + r;
          if ((pm >> kl) & 1) sc[a][r] = -1e30f;
        }
    }

    float smax = sc[0][0];
    #pragma unroll
    for (int a = 0; a < 4; ++a)
      #pragma unroll
      for (int r = 0; r < 4; ++r) smax = fmaxf(smax, sc[a][r]);
    smax = fmaxf(smax, __shfl_xor(smax, 16));
    smax = fmaxf(smax, __shfl_xor(smax, 32));
    const float mn = fmaxf(m_, smax);
    const float al = exp2f(m_ - mn);
    float ps = 0.f;
    #pragma unroll
    for (int a = 0; a < 4; ++a)
      #pragma unroll
      for (int r = 0; r < 4; ++r) {
        const float p = exp2f(sc[a][r] - mn);
        sc[a][r] = p;
        ps += p;
      }
    ps += __shfl_xor(ps, 16);
    ps += __shfl_xor(ps, 32);
    l_ = l_ * al + ps;
    m_ = mn;
    #pragma unroll
    for (int t = 0; t < 4; ++t)
      #pragma unroll
      for (int r = 0; r < 4; ++r) oacc[t][r] *= al;

    #pragma unroll
    for (int a = 0; a < 4; ++a)
      #pragma unroll
      for (int j = 0; j < 2; ++j) {
        bf16x2 w;
        w[0] = (bf16_t)sc[a][2 * j];
        w[1] = (bf16_t)sc[a][2 * j + 1];
        const int off = a * 16 + 4 * kgp + 2 * j;
        *(bf16x2*)&p_lds[wid][fr * 64 + (((off >> 3) ^ (fr & 7)) << 3) + (off & 7)] = w;
      }
    const bf16x8 pa0 = *(const bf16x8*)&p_lds[wid][swz8(fr, kgp)];
    const bf16x8 pa1 = *(const bf16x8*)&p_lds[wid][swz8(fr, 4 + kgp)];

    #pragma unroll
    for (int t = 0; t < 4; ++t) {
      const bf16x8 vb0 = *(const bf16x8*)&vt_lds[swz8(t * 16 + fr, kgp)];
      const bf16x8 vb1 = *(const bf16x8*)&vt_lds[swz8(t * 16 + fr, 4 + kgp)];
      oacc[t] = __builtin_amdgcn_mfma_f32_16x16x32_bf16(vb0, pa0, oacc[t], 0, 0, 0);
      oacc[t] = __builtin_amdgcn_mfma_f32_16x16x32_bf16(vb1, pa1, oacc[t], 0, 0, 0);
    }

    if (more) {
      __syncthreads();
      *(bf16x8*)&k_lds[swz8(srow, sc4)]      = nk0;
      *(bf16x8*)&k_lds[swz8(srow, 4 + sc4)]  = nk1;
      *(bf16x8*)&vt_lds[swz8(srow, sc4)]     = nv0;
      *(bf16x8*)&vt_lds[swz8(srow, 4 + sc4)] = nv1;
      __syncthreads();
    }
  }

  const float inv = 1.0f / l_;
  #pragma unroll
  for (int t = 0; t < 4; ++t) {
    bf16x4 o4;
    #pragma unroll
    for (int r = 0; r < 4; ++r) o4[r] = (bf16_t)(oacc[t][r] * inv);
    *(bf16x4*)&ao[(size_t)(q0 + fr) * 2048 + h * 64 + t * 16 + 4 * kgp] = o4;
  }
}

// ---------------- launcher ----------------
extern "C" void kernel_launch(void* const* d_in, const int* in_sizes, int n_in,
                              void* d_out, int out_size, void* d_ws, size_t ws_size,
                              hipStream_t stream) {
  const float* Q  = (const float*)d_in[0];
  const float* K  = (const float*)d_in[1];
  const float* V  = (const float*)d_in[2];
  const int*   am = (const int*)d_in[3];
  const float* Wq = (const float*)d_in[4];
  const float* Wk = (const float*)d_in[5];
  const float* Wv = (const float*)d_in[6];
  const float* Wo = (const float*)d_in[7];
  const float* bo = (const float*)d_in[8];
  float* out = (float*)d_out;

  const int S = 2048, D = 2048, KV = 512;
  char* w = (char*)d_ws;
  const size_t MB = 1u << 20;
  bf16_t* WqT = (bf16_t*)(w + 0 * MB);   // [D][D]
  bf16_t* WoT = (bf16_t*)(w + 8 * MB);   // [D][D]
  bf16_t* WkT = (bf16_t*)(w + 16 * MB);  // [KV][D]
  bf16_t* WvT = (bf16_t*)(w + 18 * MB);
  bf16_t* qh  = (bf16_t*)(w + 20 * MB);  // [32][S][64]
  bf16_t* kgr = (bf16_t*)(w + 28 * MB);  // [8][S][64]
  bf16_t* vtg = (bf16_t*)(w + 30 * MB);  // [8][64][S]
  bf16_t* ao  = (bf16_t*)(w + 32 * MB);  // [S][D]
  bf16_t* Qb  = (bf16_t*)(w + 40 * MB);  // [S][D] bf16
  bf16_t* Kb  = (bf16_t*)(w + 48 * MB);
  bf16_t* Vb  = (bf16_t*)(w + 56 * MB);
  float*  cs  = (float*)(w + 64 * MB);   // [S][32]
  float*  sn  = (float*)(w + 64 * MB + 256 * 1024);

  rope_table_k<<<256, 256, 0, stream>>>(cs, sn, S);
  cast3_k<<<6144, 256, 0, stream>>>(Q, K, V, Qb, Kb, Vb);
  dim3 tb(32, 8);
  transpose_cast_k<<<dim3(64, 64), tb, 0, stream>>>(Wq, WqT, D, D);
  transpose_cast_k<<<dim3(16, 64), tb, 0, stream>>>(Wk, WkT, D, KV);
  transpose_cast_k<<<dim3(16, 64), tb, 0, stream>>>(Wv, WvT, D, KV);
  transpose_cast_k<<<dim3(64, 64), tb, 0, stream>>>(Wo, WoT, D, D);

  // fused Q+K+V projections (bf16 A): 768 blocks, XCD-chunked
  gemm2_k<<<768, 256, 0, stream>>>(Qb, Kb, Vb, WqT, WkT, WvT, D, D, 5,
                                   cs, sn, qh, kgr, vtg, nullptr, nullptr, S, 24, 768);

  attn_k<<<dim3(32, 32), 256, 0, stream>>>(qh, kgr, vtg, am, ao, S);

  // O-proj: 512 blocks, XCD-chunked
  gemm2_k<<<512, 256, 0, stream>>>(ao, nullptr, nullptr, WoT, nullptr, nullptr,
                                   D, D, 3, nullptr, nullptr, nullptr, nullptr,
                                   nullptr, out, bo, S, 16, 512);
}